// Round 10
// baseline (879.596 us; speedup 1.0000x reference)
//
#include <hip/hip_runtime.h>

#define D_FEAT 1024
#define NTOK   4096
#define SEQ    2048
#define NHEAD  16
#define DK     64
#define QSCALE 0.1803368801111204f  // 0.125 * log2(e)
#define GRID   1024

typedef float          f32x4  __attribute__((ext_vector_type(4)));
typedef float          f32x16 __attribute__((ext_vector_type(16)));
typedef short          s16x8  __attribute__((ext_vector_type(8)));
typedef unsigned short u16x4  __attribute__((ext_vector_type(4)));

__device__ __forceinline__ unsigned short f2bf(float f) {
  union { float f; unsigned int u; } x; x.f = f;
  unsigned int r = x.u + 0x7fffu + ((x.u >> 16) & 1u);
  return (unsigned short)(r >> 16);
}
__device__ __forceinline__ unsigned short f2h(float f) {
  union { _Float16 h; unsigned short u; } x; x.h = (_Float16)f; return x.u;
}
__device__ __forceinline__ float h2f(unsigned short u) {
  union { _Float16 h; unsigned short u; } x; x.u = u; return (float)x.h;
}

__device__ __forceinline__ f32x4 mfma16(s16x8 a, s16x8 b, f32x4 c) {
  return __builtin_amdgcn_mfma_f32_16x16x32_bf16(a, b, c, 0, 0, 0);
}
__device__ __forceinline__ f32x16 mfma32(s16x8 a, s16x8 b, f32x16 c) {
  return __builtin_amdgcn_mfma_f32_32x32x16_bf16(a, b, c, 0, 0, 0);
}

__device__ __forceinline__ void gload16(const void* g, void* l) {
  __builtin_amdgcn_global_load_lds(
      (const __attribute__((address_space(1))) void*)g,
      (__attribute__((address_space(3))) void*)l, 16, 0, 0);
}

// device-scope grid barrier: arrival count + RMW spin (coherent point),
// fences for cross-XCD visibility of prior-phase stores. Requires all
// gridDim blocks co-resident (grid 1024 @ launch_bounds(256,4) = exact fill).
__device__ __forceinline__ void gbar(unsigned* cnt, unsigned target) {
  __syncthreads();
  if (threadIdx.x == 0) {
    __threadfence();
    atomicAdd(cnt, 1u);
    while (atomicAdd(cnt, 0u) < target) __builtin_amdgcn_s_sleep(2);
    __threadfence();
  }
  __syncthreads();
}

__global__ __launch_bounds__(256, 4) void mega_kernel(
    const float* __restrict__ q, const float* __restrict__ k, const float* __restrict__ v,
    const float* __restrict__ Wq, const float* __restrict__ Wk,
    const float* __restrict__ Wv, const float* __restrict__ Wo,
    const float* __restrict__ bq, const float* __restrict__ bk,
    const float* __restrict__ bv, const float* __restrict__ bo,
    const float* __restrict__ gamma, const float* __restrict__ beta,
    unsigned short* qb, unsigned short* kb, unsigned short* vb,
    unsigned short* WT, unsigned short* Wot,
    unsigned short* Qp, unsigned short* Kp, unsigned short* Vt,
    unsigned short* Opart, float* L, unsigned short* ctx, float* tmp,
    float* out, unsigned* bar)
{
  __shared__ __align__(16) unsigned char smem[32768];
  const int tid = threadIdx.x;
  const int blk = blockIdx.x;
  const int wave = tid >> 6, lane = tid & 63;
  const int quad = lane >> 4, l16 = lane & 15;
  const int rw8 = lane >> 3;
  const int cls = ((lane & 7) ^ (lane >> 3)) * 8;   // swizzled source chunk

  // ================= P0: cast q/k/v -> bf16, transpose+cast weights =================
  {
    float (*tile)[33] = (float(*)[33])smem;
    for (int u = blk; u < 16384; u += GRID) {
      if (u < 12288) {
        int sel = u >> 12;
        const float* src = sel == 0 ? q : (sel == 1 ? k : v);
        unsigned short* dst = sel == 0 ? qb : (sel == 1 ? kb : vb);
        size_t i = ((size_t)(u & 4095) * 256 + tid) * 4;
        float4 f = *(const float4*)(src + i);
        u16x4 o; o.x = f2bf(f.x); o.y = f2bf(f.y); o.z = f2bf(f.z); o.w = f2bf(f.w);
        *(u16x4*)(dst + i) = o;
      } else {
        int t = u - 12288;
        int z = t >> 10, rest = t & 1023;
        int bxt = rest & 31, byt = rest >> 5;
        const float* W = z == 0 ? Wq : z == 1 ? Wk : z == 2 ? Wv : Wo;
        unsigned short* T = (z < 3) ? (WT + (size_t)z * 1024 * 1024) : Wot;
        int tx = tid & 31, ty = tid >> 5;
        for (int i2 = 0; i2 < 4; ++i2)
          tile[ty + i2 * 8][tx] =
              W[(size_t)(byt * 32 + ty + i2 * 8) * D_FEAT + bxt * 32 + tx];
        __syncthreads();
        int n_loc = tid >> 3, kc = (tid & 7) * 4;
        u16x4 ovv;
        for (int j = 0; j < 4; ++j) ovv[j] = f2bf(tile[kc + j][n_loc]);
        *(u16x4*)(T + (size_t)(bxt * 32 + n_loc) * D_FEAT + byt * 32 + kc) = ovv;
        __syncthreads();
      }
    }
  }
  gbar(bar, 1 * GRID);

  // ================= P1: fused QKV projection GEMM (768 active blocks) =================
  if (blk < 768) {
    unsigned short* sA = (unsigned short*)smem;
    unsigned short* sB = (unsigned short*)smem + 128 * 64;
    const int wx = wave & 1, wy = wave >> 1;
    const int xcd = blk & 7, jj = blk >> 3;
    const int chunk = jj >> 5;
    const int rest = jj & 31;
    const int n0i = rest & 7;
    const int by  = xcd * 4 + (rest >> 3);

    const unsigned short* rA;
    const unsigned short* rB;
    int m0, n0;
    if (chunk < 2) {
      m0 = by * 128; n0 = n0i * 128;
      rA = (chunk ? kb : qb) + (size_t)m0 * D_FEAT;
      rB = WT + (size_t)(chunk * 1024 + n0) * D_FEAT;
    } else {
      m0 = n0i * 128; n0 = by * 128;
      rA = WT + (size_t)(2048 + m0) * D_FEAT;
      rB = vb + (size_t)n0 * D_FEAT;
    }

    f32x4 acc[4][4];
    for (int mt = 0; mt < 4; ++mt)
      for (int nt = 0; nt < 4; ++nt) acc[mt][nt] = (f32x4){0.f, 0.f, 0.f, 0.f};

    const int sw = l16 & 7;
    for (int k0 = 0; k0 < D_FEAT; k0 += 64) {
      __syncthreads();
      for (int j = 0; j < 4; ++j) {
        int ch = wave * 4 + j;
        gload16(rA + (size_t)(ch * 8 + rw8) * D_FEAT + k0 + cls, sA + ch * 512);
        gload16(rB + (size_t)(ch * 8 + rw8) * D_FEAT + k0 + cls, sB + ch * 512);
      }
      __syncthreads();
      for (int kk = 0; kk < 2; ++kk) {
        int c = ((kk * 4 + quad) ^ sw) * 8;
        s16x8 af[4], bfr[4];
        for (int mt = 0; mt < 4; ++mt)
          af[mt] = *(const s16x8*)(sA + (wy * 64 + mt * 16 + l16) * 64 + c);
        for (int nt = 0; nt < 4; ++nt)
          bfr[nt] = *(const s16x8*)(sB + (wx * 64 + nt * 16 + l16) * 64 + c);
        for (int mt = 0; mt < 4; ++mt)
          for (int nt = 0; nt < 4; ++nt)
            acc[mt][nt] = mfma16(af[mt], bfr[nt], acc[mt][nt]);
      }
    }

    if (chunk < 2) {
      const float* bias = chunk ? bk : bq;
      unsigned short* Cp = chunk ? Kp : Qp;
      const float scale = chunk == 0 ? QSCALE : 1.0f;
      for (int mt = 0; mt < 4; ++mt)
        for (int nt = 0; nt < 4; ++nt) {
          int col = n0 + wx * 64 + nt * 16 + l16;
          float bcol = bias[col];
          for (int r = 0; r < 4; ++r) {
            int row = m0 + wy * 64 + mt * 16 + quad * 4 + r;
            Cp[(size_t)row * D_FEAT + col] = f2bf((acc[mt][nt][r] + bcol) * scale);
          }
        }
    } else {
      for (int mt = 0; mt < 4; ++mt)
        for (int r = 0; r < 4; ++r) {
          float bfeat = bv[m0 + wy * 64 + mt * 16 + quad * 4 + r];
          for (int nt = 0; nt < 4; ++nt) acc[mt][nt][r] += bfeat;
        }
      unsigned short* tb = (unsigned short*)smem;
      for (int p = 0; p < 2; ++p) {
        __syncthreads();
        if (wx == p) {
          for (int mt = 0; mt < 4; ++mt)
            for (int nt = 0; nt < 4; ++nt) {
              int tok_loc = nt * 16 + l16;
              for (int r = 0; r < 4; ++r) {
                int f_loc = wy * 64 + mt * 16 + quad * 4 + r;
                tb[f_loc * 72 + tok_loc] = f2bf(acc[mt][nt][r]);
              }
            }
        }
        __syncthreads();
        int n_base = n0 + p * 64;
        int b = n_base >> 11, tok0 = n_base & 2047;
        int ck = lane & 7;
        for (int j = 0; j < 4; ++j) {
          int f_loc = (wave * 4 + j) * 8 + rw8;
          int f = m0 + f_loc, hh = f >> 6, dv = f & 63;
          *(s16x8*)(Vt + ((size_t)(b * 16 + hh) * 64 + dv) * SEQ + tok0 + ck * 8) =
              *(const s16x8*)(tb + f_loc * 72 + ck * 8);
        }
      }
    }
  }
  gbar(bar, 2 * GRID);

  // ================= P2: flash attention split-S (all 1024 blocks) =================
  {
    unsigned short* sQ = (unsigned short*)smem;            // reused as sP
    unsigned short* sK = sQ + 128 * 64;
    unsigned short* sV = sK + 64 * 64;                     // [dv][key]
    const int l32 = lane & 31, h = lane >> 5;

    const int xcd = blk & 7, jj = blk >> 3;
    const int grp = xcd * 8 + (jj >> 4);     // (bh,z) group 0..63
    const int q0 = (jj & 15) * 128;
    const int bh = grp & 31, z = grp >> 5;
    const int b = bh >> 4, hd = bh & 15;
    const int kbase = z * (SEQ / 2);
    const size_t base = (size_t)b * SEQ * D_FEAT + (size_t)hd * DK;
    const unsigned short* vt = Vt + (size_t)bh * 64 * SEQ;

    for (int j = 0; j < 4; ++j) {
      int ch = wave * 4 + j;
      gload16(Qp + base + (size_t)(q0 + ch * 8 + rw8) * D_FEAT + cls, sQ + ch * 512);
    }
    __syncthreads();

    const int qrow = wave * 32 + l32;
    const int qsw = qrow & 7;
    s16x8 bqf[4];
    for (int s = 0; s < 4; ++s)
      bqf[s] = *(const s16x8*)(sQ + qrow * 64 + ((2 * s + h) ^ qsw) * 8);

    unsigned short* sP = sQ;  // wave-private rows qrow

    f32x16 o0, o1;
    for (int r = 0; r < 16; ++r) { o0[r] = 0.f; o1[r] = 0.f; }
    float lsum = 0.f;
    const int ksw0 = l32 & 7;

    for (int k0 = kbase; k0 < kbase + SEQ / 2; k0 += 64) {
      __syncthreads();
      for (int j = 0; j < 2; ++j) {
        int ch = wave * 2 + j;
        gload16(Kp + base + (size_t)(k0 + ch * 8 + rw8) * D_FEAT + cls, sK + ch * 512);
        gload16(vt + (size_t)(ch * 8 + rw8) * SEQ + k0 + cls, sV + ch * 512);
      }
      __syncthreads();

      f32x16 st0, st1;
      for (int r = 0; r < 16; ++r) { st0[r] = 0.f; st1[r] = 0.f; }
      for (int s = 0; s < 4; ++s) {
        int csw = ((2 * s + h) ^ ksw0) * 8;
        s16x8 a0 = *(const s16x8*)(sK + l32 * 64 + csw);
        s16x8 a1 = *(const s16x8*)(sK + (32 + l32) * 64 + csw);
        st0 = mfma32(a0, bqf[s], st0);
        st1 = mfma32(a1, bqf[s], st1);
      }

      const int rowb = qrow * 64;
      for (int g = 0; g < 4; ++g) {
        unsigned int u[4];
        for (int r = 0; r < 4; ++r) {
          union { float f; unsigned int v; } x;
          x.f = __builtin_exp2f(st0[4 * g + r]);
          lsum += x.f; u[r] = x.v;
        }
        unsigned int w0 = __builtin_amdgcn_perm(u[1], u[0], 0x07060302u);
        unsigned int w1 = __builtin_amdgcn_perm(u[3], u[2], 0x07060302u);
        *(uint2*)(sP + rowb + ((g ^ qsw) * 8) + 4 * h) = make_uint2(w0, w1);
      }
      for (int g = 0; g < 4; ++g) {
        unsigned int u[4];
        for (int r = 0; r < 4; ++r) {
          union { float f; unsigned int v; } x;
          x.f = __builtin_exp2f(st1[4 * g + r]);
          lsum += x.f; u[r] = x.v;
        }
        unsigned int w0 = __builtin_amdgcn_perm(u[1], u[0], 0x07060302u);
        unsigned int w1 = __builtin_amdgcn_perm(u[3], u[2], 0x07060302u);
        *(uint2*)(sP + rowb + (((4 + g) ^ qsw) * 8) + 4 * h) = make_uint2(w0, w1);
      }

      s16x8 bp[4];
      for (int s = 0; s < 4; ++s)
        bp[s] = *(const s16x8*)(sP + rowb + ((2 * s + h) ^ qsw) * 8);

      for (int s = 0; s < 4; ++s) {
        int csw = ((2 * s + h) ^ ksw0) * 8;
        s16x8 a0 = *(const s16x8*)(sV + l32 * 64 + csw);
        s16x8 a1 = *(const s16x8*)(sV + (32 + l32) * 64 + csw);
        o0 = mfma32(a0, bp[s], o0);
        o1 = mfma32(a1, bp[s], o1);
      }
    }

    lsum += __shfl_xor(lsum, 32, 64);
    const size_t trow = (size_t)(z * 32 + bh) * SEQ + (q0 + qrow);
    unsigned short* orow = Opart + trow * 64;
    for (int g = 0; g < 4; ++g) {
      u16x4 ov;
      for (int r = 0; r < 4; ++r) ov[r] = f2h(o0[4 * g + r]);
      *(u16x4*)(orow + 8 * g + 4 * h) = ov;
    }
    for (int g = 0; g < 4; ++g) {
      u16x4 ov;
      for (int r = 0; r < 4; ++r) ov[r] = f2h(o1[4 * g + r]);
      *(u16x4*)(orow + 32 + 8 * g + 4 * h) = ov;
    }
    if (h == 0) L[trow] = lsum;
  }
  gbar(bar, 3 * GRID);

  // ================= P3: combine halves -> ctx =================
  {
    const int HS = 32 * SEQ;
    for (int i = 0; i < 4; ++i) {
      int idx = (blk + GRID * i) * 256 + tid;
      int dq = idx & 15;
      int trow = idx >> 4;
      int bh = trow >> 11, tok = trow & 2047;
      int b = bh >> 4, h = bh & 15;
      float inv = __builtin_amdgcn_rcpf(L[trow] + L[HS + trow]);
      u16x4 p0 = *(const u16x4*)(Opart + (size_t)trow * 64 + dq * 4);
      u16x4 p1 = *(const u16x4*)(Opart + ((size_t)HS + trow) * 64 + dq * 4);
      u16x4 o;
      for (int r = 0; r < 4; ++r)
        o[r] = f2bf((h2f(p0[r]) + h2f(p1[r])) * inv);
      *(u16x4*)(ctx + (size_t)b * SEQ * D_FEAT + (size_t)tok * D_FEAT +
                h * 64 + dq * 4) = o;
    }
  }
  gbar(bar, 4 * GRID);

  // ================= P4: out-projection + bias + residual (512 active) =================
  if (blk < 512) {
    unsigned short* sA = (unsigned short*)smem;
    unsigned short* sB = (unsigned short*)smem + 128 * 64;
    const int wx = wave & 1, wy = wave >> 1;
    const int xcd = blk & 7, jj = blk >> 3;
    const int n0 = (jj & 15) * 64;
    const int m0 = (xcd * 4 + (jj >> 4)) * 128;

    f32x4 acc[4][2];
    for (int mt = 0; mt < 4; ++mt)
      for (int nt = 0; nt < 2; ++nt) acc[mt][nt] = (f32x4){0.f, 0.f, 0.f, 0.f};

    const int sw = l16 & 7;
    for (int k0 = 0; k0 < D_FEAT; k0 += 64) {
      __syncthreads();
      for (int j = 0; j < 4; ++j) {
        int ch = wave * 4 + j;
        gload16(ctx + (size_t)(m0 + ch * 8 + rw8) * D_FEAT + k0 + cls, sA + ch * 512);
      }
      for (int j = 0; j < 2; ++j) {
        int ch = wave * 2 + j;
        gload16(Wot + (size_t)(n0 + ch * 8 + rw8) * D_FEAT + k0 + cls, sB + ch * 512);
      }
      __syncthreads();
      for (int kk = 0; kk < 2; ++kk) {
        int c = ((kk * 4 + quad) ^ sw) * 8;
        s16x8 af[4], bfr[2];
        for (int mt = 0; mt < 4; ++mt)
          af[mt] = *(const s16x8*)(sA + (wy * 64 + mt * 16 + l16) * 64 + c);
        for (int nt = 0; nt < 2; ++nt)
          bfr[nt] = *(const s16x8*)(sB + (wx * 32 + nt * 16 + l16) * 64 + c);
        for (int mt = 0; mt < 4; ++mt)
          for (int nt = 0; nt < 2; ++nt)
            acc[mt][nt] = mfma16(af[mt], bfr[nt], acc[mt][nt]);
      }
    }

    for (int mt = 0; mt < 4; ++mt)
      for (int nt = 0; nt < 2; ++nt) {
        int col = n0 + wx * 32 + nt * 16 + l16;
        float bcol = bo[col];
        for (int r = 0; r < 4; ++r) {
          int row = m0 + wy * 64 + mt * 16 + quad * 4 + r;
          tmp[(size_t)row * D_FEAT + col] =
              acc[mt][nt][r] + bcol + v[(size_t)row * D_FEAT + col];
        }
      }
  }
  gbar(bar, 5 * GRID);

  // ================= P5: LayerNorm =================
  {
    float* red = (float*)smem;
    for (int i = 0; i < 4; ++i) {
      int row = blk * 4 + i;
      const float* xr = tmp + (size_t)row * D_FEAT;
      float4 vv = ((const float4*)xr)[tid];
      float s  = vv.x + vv.y + vv.z + vv.w;
      float ss = vv.x * vv.x + vv.y * vv.y + vv.z * vv.z + vv.w * vv.w;
      for (int off = 1; off < 64; off <<= 1) {
        s  += __shfl_xor(s,  off, 64);
        ss += __shfl_xor(ss, off, 64);
      }
      if (lane == 0) { red[wave] = s; red[wave + 4] = ss; }
      __syncthreads();
      s  = red[0] + red[1] + red[2] + red[3];
      ss = red[4] + red[5] + red[6] + red[7];
      float mean = s * (1.f / D_FEAT);
      float var  = ss * (1.f / D_FEAT) - mean * mean;
      float rstd = rsqrtf(var + 1e-6f);
      float4 g  = ((const float4*)gamma)[tid];
      float4 bt = ((const float4*)beta)[tid];
      float4 o;
      o.x = (vv.x - mean) * rstd * g.x + bt.x;
      o.y = (vv.y - mean) * rstd * g.y + bt.y;
      o.z = (vv.z - mean) * rstd * g.z + bt.z;
      o.w = (vv.w - mean) * rstd * g.w + bt.w;
      ((float4*)(out + (size_t)row * D_FEAT))[tid] = o;
      __syncthreads();
    }
  }
}

extern "C" void kernel_launch(void* const* d_in, const int* in_sizes, int n_in,
                              void* d_out, int out_size, void* d_ws, size_t ws_size,
                              hipStream_t stream) {
  const float* q     = (const float*)d_in[0];
  const float* k     = (const float*)d_in[1];
  const float* v     = (const float*)d_in[2];
  const float* Wq    = (const float*)d_in[3];
  const float* bq    = (const float*)d_in[4];
  const float* Wk    = (const float*)d_in[5];
  const float* bk    = (const float*)d_in[6];
  const float* Wv    = (const float*)d_in[7];
  const float* bv    = (const float*)d_in[8];
  const float* Wo    = (const float*)d_in[9];
  const float* bo    = (const float*)d_in[10];
  const float* gamma = (const float*)d_in[11];
  const float* beta  = (const float*)d_in[12];

  char* w = (char*)d_ws;
  const size_t MB = 1u << 20;
  // P0/P1: qb 0-8, kb 8-16, vb 16-24, WT 24-30, Wot 30-32
  // P2:    Opart 0-16 (over dead qb/kb), L 16-16.5 (over dead vb)
  // P1/P2: Qp 32-40, Kp 40-48, Vt 48-56
  // P3:    ctx 56-64
  // P4/P5: tmp 32-48 (over dead Qp/Kp)
  // barrier counter at 64 MB (region 64+ unused)
  unsigned short* qb    = (unsigned short*)(w + 0 * MB);
  unsigned short* kb    = (unsigned short*)(w + 8 * MB);
  unsigned short* vb    = (unsigned short*)(w + 16 * MB);
  unsigned short* WT    = (unsigned short*)(w + 24 * MB);
  unsigned short* Wot   = (unsigned short*)(w + 30 * MB);
  unsigned short* Qp    = (unsigned short*)(w + 32 * MB);
  unsigned short* Kp    = (unsigned short*)(w + 40 * MB);
  unsigned short* Vt    = (unsigned short*)(w + 48 * MB);
  unsigned short* ctx   = (unsigned short*)(w + 56 * MB);
  unsigned short* Opart = (unsigned short*)(w + 0 * MB);
  float*          L     = (float*)(w + 16 * MB);
  float*          tmp   = (float*)(w + 32 * MB);
  unsigned*       bar   = (unsigned*)(w + 64 * MB);

  hipMemsetAsync(bar, 0, 64, stream);

  mega_kernel<<<GRID, 256, 0, stream>>>(
      q, k, v, Wq, Wk, Wv, Wo, bq, bk, bv, bo, gamma, beta,
      qb, kb, vb, WT, Wot, Qp, Kp, Vt, Opart, L, ctx, tmp,
      (float*)d_out, bar);
}

// Round 11
// 854.882 us; speedup vs baseline: 1.0289x; 1.0289x over previous
//
#include <hip/hip_runtime.h>

#define D_FEAT 1024
#define NTOK   4096
#define SEQ    2048
#define NHEAD  16
#define DK     64
#define QSCALE 0.1803368801111204f  // 0.125 * log2(e)
#define GRID   1024

typedef float          f32x4  __attribute__((ext_vector_type(4)));
typedef float          f32x16 __attribute__((ext_vector_type(16)));
typedef short          s16x8  __attribute__((ext_vector_type(8)));
typedef unsigned short u16x4  __attribute__((ext_vector_type(4)));

__device__ __forceinline__ unsigned short f2bf(float f) {
  union { float f; unsigned int u; } x; x.f = f;
  unsigned int r = x.u + 0x7fffu + ((x.u >> 16) & 1u);
  return (unsigned short)(r >> 16);
}
__device__ __forceinline__ unsigned short f2h(float f) {
  union { _Float16 h; unsigned short u; } x; x.h = (_Float16)f; return x.u;
}
__device__ __forceinline__ float h2f(unsigned short u) {
  union { _Float16 h; unsigned short u; } x; x.u = u; return (float)x.h;
}

__device__ __forceinline__ f32x4 mfma16(s16x8 a, s16x8 b, f32x4 c) {
  return __builtin_amdgcn_mfma_f32_16x16x32_bf16(a, b, c, 0, 0, 0);
}
__device__ __forceinline__ f32x16 mfma32(s16x8 a, s16x8 b, f32x16 c) {
  return __builtin_amdgcn_mfma_f32_32x32x16_bf16(a, b, c, 0, 0, 0);
}

__device__ __forceinline__ void gload16(const void* g, void* l) {
  __builtin_amdgcn_global_load_lds(
      (const __attribute__((address_space(1))) void*)g,
      (__attribute__((address_space(3))) void*)l, 16, 0, 0);
}

// device-scope grid barrier. Arrival: one atomicAdd per block. Poll: device-
// scope atomic LOAD (no RMW -- R10's atomicAdd(cnt,0) poll serialized at the
// coherence point and cost ~110us/barrier). Per-phase counters 64B apart.
__device__ __forceinline__ void gbar(unsigned* cnt) {
  __syncthreads();
  if (threadIdx.x == 0) {
    __threadfence();
    atomicAdd(cnt, 1u);
    while (__hip_atomic_load(cnt, __ATOMIC_RELAXED, __HIP_MEMORY_SCOPE_AGENT) < GRID)
      __builtin_amdgcn_s_sleep(4);
    __threadfence();
  }
  __syncthreads();
}

__global__ __launch_bounds__(256, 4) void mega_kernel(
    const float* __restrict__ q, const float* __restrict__ k, const float* __restrict__ v,
    const float* __restrict__ Wq, const float* __restrict__ Wk,
    const float* __restrict__ Wv, const float* __restrict__ Wo,
    const float* __restrict__ bq, const float* __restrict__ bk,
    const float* __restrict__ bv, const float* __restrict__ bo,
    const float* __restrict__ gamma, const float* __restrict__ beta,
    unsigned short* qb, unsigned short* kb, unsigned short* vb,
    unsigned short* WT, unsigned short* Wot,
    unsigned short* Qp, unsigned short* Kp, unsigned short* Vt,
    unsigned short* Opart, float* L, unsigned short* ctx, float* tmp,
    float* out, unsigned* bar)
{
  __shared__ __align__(16) unsigned char smem[32768];
  const int tid = threadIdx.x;
  const int blk = blockIdx.x;
  const int wave = tid >> 6, lane = tid & 63;
  const int quad = lane >> 4, l16 = lane & 15;
  const int rw8 = lane >> 3;
  const int cls = ((lane & 7) ^ (lane >> 3)) * 8;   // swizzled source chunk

  // ================= P0: cast q/k/v -> bf16, transpose+cast weights =================
  {
    float (*tile)[33] = (float(*)[33])smem;
    for (int u = blk; u < 16384; u += GRID) {
      if (u < 12288) {
        int sel = u >> 12;
        const float* src = sel == 0 ? q : (sel == 1 ? k : v);
        unsigned short* dst = sel == 0 ? qb : (sel == 1 ? kb : vb);
        size_t i = ((size_t)(u & 4095) * 256 + tid) * 4;
        float4 f = *(const float4*)(src + i);
        u16x4 o; o.x = f2bf(f.x); o.y = f2bf(f.y); o.z = f2bf(f.z); o.w = f2bf(f.w);
        *(u16x4*)(dst + i) = o;
      } else {
        int t = u - 12288;
        int z = t >> 10, rest = t & 1023;
        int bxt = rest & 31, byt = rest >> 5;
        const float* W = z == 0 ? Wq : z == 1 ? Wk : z == 2 ? Wv : Wo;
        unsigned short* T = (z < 3) ? (WT + (size_t)z * 1024 * 1024) : Wot;
        int tx = tid & 31, ty = tid >> 5;
        for (int i2 = 0; i2 < 4; ++i2)
          tile[ty + i2 * 8][tx] =
              W[(size_t)(byt * 32 + ty + i2 * 8) * D_FEAT + bxt * 32 + tx];
        __syncthreads();
        int n_loc = tid >> 3, kc = (tid & 7) * 4;
        u16x4 ovv;
        for (int j = 0; j < 4; ++j) ovv[j] = f2bf(tile[kc + j][n_loc]);
        *(u16x4*)(T + (size_t)(bxt * 32 + n_loc) * D_FEAT + byt * 32 + kc) = ovv;
        __syncthreads();
      }
    }
  }
  gbar(bar + 0 * 16);

  // ================= P1: fused QKV projection GEMM (768 active blocks) =================
  if (blk < 768) {
    unsigned short* sA = (unsigned short*)smem;
    unsigned short* sB = (unsigned short*)smem + 128 * 64;
    const int wx = wave & 1, wy = wave >> 1;
    const int xcd = blk & 7, jj = blk >> 3;
    const int chunk = jj >> 5;
    const int rest = jj & 31;
    const int n0i = rest & 7;
    const int by  = xcd * 4 + (rest >> 3);

    const unsigned short* rA;
    const unsigned short* rB;
    int m0, n0;
    if (chunk < 2) {
      m0 = by * 128; n0 = n0i * 128;
      rA = (chunk ? kb : qb) + (size_t)m0 * D_FEAT;
      rB = WT + (size_t)(chunk * 1024 + n0) * D_FEAT;
    } else {
      m0 = n0i * 128; n0 = by * 128;
      rA = WT + (size_t)(2048 + m0) * D_FEAT;
      rB = vb + (size_t)n0 * D_FEAT;
    }

    f32x4 acc[4][4];
    for (int mt = 0; mt < 4; ++mt)
      for (int nt = 0; nt < 4; ++nt) acc[mt][nt] = (f32x4){0.f, 0.f, 0.f, 0.f};

    const int sw = l16 & 7;
    for (int k0 = 0; k0 < D_FEAT; k0 += 64) {
      __syncthreads();
      for (int j = 0; j < 4; ++j) {
        int ch = wave * 4 + j;
        gload16(rA + (size_t)(ch * 8 + rw8) * D_FEAT + k0 + cls, sA + ch * 512);
        gload16(rB + (size_t)(ch * 8 + rw8) * D_FEAT + k0 + cls, sB + ch * 512);
      }
      __syncthreads();
      for (int kk = 0; kk < 2; ++kk) {
        int c = ((kk * 4 + quad) ^ sw) * 8;
        s16x8 af[4], bfr[4];
        for (int mt = 0; mt < 4; ++mt)
          af[mt] = *(const s16x8*)(sA + (wy * 64 + mt * 16 + l16) * 64 + c);
        for (int nt = 0; nt < 4; ++nt)
          bfr[nt] = *(const s16x8*)(sB + (wx * 64 + nt * 16 + l16) * 64 + c);
        for (int mt = 0; mt < 4; ++mt)
          for (int nt = 0; nt < 4; ++nt)
            acc[mt][nt] = mfma16(af[mt], bfr[nt], acc[mt][nt]);
      }
    }

    if (chunk < 2) {
      const float* bias = chunk ? bk : bq;
      unsigned short* Cp = chunk ? Kp : Qp;
      const float scale = chunk == 0 ? QSCALE : 1.0f;
      for (int mt = 0; mt < 4; ++mt)
        for (int nt = 0; nt < 4; ++nt) {
          int col = n0 + wx * 64 + nt * 16 + l16;
          float bcol = bias[col];
          for (int r = 0; r < 4; ++r) {
            int row = m0 + wy * 64 + mt * 16 + quad * 4 + r;
            Cp[(size_t)row * D_FEAT + col] = f2bf((acc[mt][nt][r] + bcol) * scale);
          }
        }
    } else {
      for (int mt = 0; mt < 4; ++mt)
        for (int r = 0; r < 4; ++r) {
          float bfeat = bv[m0 + wy * 64 + mt * 16 + quad * 4 + r];
          for (int nt = 0; nt < 4; ++nt) acc[mt][nt][r] += bfeat;
        }
      unsigned short* tb = (unsigned short*)smem;
      for (int p = 0; p < 2; ++p) {
        __syncthreads();
        if (wx == p) {
          for (int mt = 0; mt < 4; ++mt)
            for (int nt = 0; nt < 4; ++nt) {
              int tok_loc = nt * 16 + l16;
              for (int r = 0; r < 4; ++r) {
                int f_loc = wy * 64 + mt * 16 + quad * 4 + r;
                tb[f_loc * 72 + tok_loc] = f2bf(acc[mt][nt][r]);
              }
            }
        }
        __syncthreads();
        int n_base = n0 + p * 64;
        int b = n_base >> 11, tok0 = n_base & 2047;
        int ck = lane & 7;
        for (int j = 0; j < 4; ++j) {
          int f_loc = (wave * 4 + j) * 8 + rw8;
          int f = m0 + f_loc, hh = f >> 6, dv = f & 63;
          *(s16x8*)(Vt + ((size_t)(b * 16 + hh) * 64 + dv) * SEQ + tok0 + ck * 8) =
              *(const s16x8*)(tb + f_loc * 72 + ck * 8);
        }
      }
    }
  }
  gbar(bar + 1 * 16);

  // ================= P2: flash attention split-S (all 1024 blocks) =================
  {
    unsigned short* sQ = (unsigned short*)smem;            // reused as sP
    unsigned short* sK = sQ + 128 * 64;
    unsigned short* sV = sK + 64 * 64;                     // [dv][key]
    const int l32 = lane & 31, h = lane >> 5;

    const int xcd = blk & 7, jj = blk >> 3;
    const int grp = xcd * 8 + (jj >> 4);     // (bh,z) group 0..63
    const int q0 = (jj & 15) * 128;
    const int bh = grp & 31, z = grp >> 5;
    const int b = bh >> 4, hd = bh & 15;
    const int kbase = z * (SEQ / 2);
    const size_t base = (size_t)b * SEQ * D_FEAT + (size_t)hd * DK;
    const unsigned short* vt = Vt + (size_t)bh * 64 * SEQ;

    for (int j = 0; j < 4; ++j) {
      int ch = wave * 4 + j;
      gload16(Qp + base + (size_t)(q0 + ch * 8 + rw8) * D_FEAT + cls, sQ + ch * 512);
    }
    __syncthreads();

    const int qrow = wave * 32 + l32;
    const int qsw = qrow & 7;
    s16x8 bqf[4];
    for (int s = 0; s < 4; ++s)
      bqf[s] = *(const s16x8*)(sQ + qrow * 64 + ((2 * s + h) ^ qsw) * 8);

    unsigned short* sP = sQ;  // wave-private rows qrow

    f32x16 o0, o1;
    for (int r = 0; r < 16; ++r) { o0[r] = 0.f; o1[r] = 0.f; }
    float lsum = 0.f;
    const int ksw0 = l32 & 7;

    for (int k0 = kbase; k0 < kbase + SEQ / 2; k0 += 64) {
      __syncthreads();
      for (int j = 0; j < 2; ++j) {
        int ch = wave * 2 + j;
        gload16(Kp + base + (size_t)(k0 + ch * 8 + rw8) * D_FEAT + cls, sK + ch * 512);
        gload16(vt + (size_t)(ch * 8 + rw8) * SEQ + k0 + cls, sV + ch * 512);
      }
      __syncthreads();

      f32x16 st0, st1;
      for (int r = 0; r < 16; ++r) { st0[r] = 0.f; st1[r] = 0.f; }
      for (int s = 0; s < 4; ++s) {
        int csw = ((2 * s + h) ^ ksw0) * 8;
        s16x8 a0 = *(const s16x8*)(sK + l32 * 64 + csw);
        s16x8 a1 = *(const s16x8*)(sK + (32 + l32) * 64 + csw);
        st0 = mfma32(a0, bqf[s], st0);
        st1 = mfma32(a1, bqf[s], st1);
      }

      const int rowb = qrow * 64;
      for (int g = 0; g < 4; ++g) {
        unsigned int u[4];
        for (int r = 0; r < 4; ++r) {
          union { float f; unsigned int v; } x;
          x.f = __builtin_exp2f(st0[4 * g + r]);
          lsum += x.f; u[r] = x.v;
        }
        unsigned int w0 = __builtin_amdgcn_perm(u[1], u[0], 0x07060302u);
        unsigned int w1 = __builtin_amdgcn_perm(u[3], u[2], 0x07060302u);
        *(uint2*)(sP + rowb + ((g ^ qsw) * 8) + 4 * h) = make_uint2(w0, w1);
      }
      for (int g = 0; g < 4; ++g) {
        unsigned int u[4];
        for (int r = 0; r < 4; ++r) {
          union { float f; unsigned int v; } x;
          x.f = __builtin_exp2f(st1[4 * g + r]);
          lsum += x.f; u[r] = x.v;
        }
        unsigned int w0 = __builtin_amdgcn_perm(u[1], u[0], 0x07060302u);
        unsigned int w1 = __builtin_amdgcn_perm(u[3], u[2], 0x07060302u);
        *(uint2*)(sP + rowb + (((4 + g) ^ qsw) * 8) + 4 * h) = make_uint2(w0, w1);
      }

      s16x8 bp[4];
      for (int s = 0; s < 4; ++s)
        bp[s] = *(const s16x8*)(sP + rowb + ((2 * s + h) ^ qsw) * 8);

      for (int s = 0; s < 4; ++s) {
        int csw = ((2 * s + h) ^ ksw0) * 8;
        s16x8 a0 = *(const s16x8*)(sV + l32 * 64 + csw);
        s16x8 a1 = *(const s16x8*)(sV + (32 + l32) * 64 + csw);
        o0 = mfma32(a0, bp[s], o0);
        o1 = mfma32(a1, bp[s], o1);
      }
    }

    lsum += __shfl_xor(lsum, 32, 64);
    const size_t trow = (size_t)(z * 32 + bh) * SEQ + (q0 + qrow);
    unsigned short* orow = Opart + trow * 64;
    for (int g = 0; g < 4; ++g) {
      u16x4 ov;
      for (int r = 0; r < 4; ++r) ov[r] = f2h(o0[4 * g + r]);
      *(u16x4*)(orow + 8 * g + 4 * h) = ov;
    }
    for (int g = 0; g < 4; ++g) {
      u16x4 ov;
      for (int r = 0; r < 4; ++r) ov[r] = f2h(o1[4 * g + r]);
      *(u16x4*)(orow + 32 + 8 * g + 4 * h) = ov;
    }
    if (h == 0) L[trow] = lsum;
  }
  gbar(bar + 2 * 16);

  // ================= P3: combine halves -> ctx =================
  {
    const int HS = 32 * SEQ;
    for (int i = 0; i < 4; ++i) {
      int idx = (blk + GRID * i) * 256 + tid;
      int dq = idx & 15;
      int trow = idx >> 4;
      int bh = trow >> 11, tok = trow & 2047;
      int b = bh >> 4, h = bh & 15;
      float inv = __builtin_amdgcn_rcpf(L[trow] + L[HS + trow]);
      u16x4 p0 = *(const u16x4*)(Opart + (size_t)trow * 64 + dq * 4);
      u16x4 p1 = *(const u16x4*)(Opart + ((size_t)HS + trow) * 64 + dq * 4);
      u16x4 o;
      for (int r = 0; r < 4; ++r)
        o[r] = f2bf((h2f(p0[r]) + h2f(p1[r])) * inv);
      *(u16x4*)(ctx + (size_t)b * SEQ * D_FEAT + (size_t)tok * D_FEAT +
                h * 64 + dq * 4) = o;
    }
  }
  gbar(bar + 3 * 16);

  // ================= P4: out-projection + bias + residual (512 active) =================
  if (blk < 512) {
    unsigned short* sA = (unsigned short*)smem;
    unsigned short* sB = (unsigned short*)smem + 128 * 64;
    const int wx = wave & 1, wy = wave >> 1;
    const int xcd = blk & 7, jj = blk >> 3;
    const int n0 = (jj & 15) * 64;
    const int m0 = (xcd * 4 + (jj >> 4)) * 128;

    f32x4 acc[4][2];
    for (int mt = 0; mt < 4; ++mt)
      for (int nt = 0; nt < 2; ++nt) acc[mt][nt] = (f32x4){0.f, 0.f, 0.f, 0.f};

    const int sw = l16 & 7;
    for (int k0 = 0; k0 < D_FEAT; k0 += 64) {
      __syncthreads();
      for (int j = 0; j < 4; ++j) {
        int ch = wave * 4 + j;
        gload16(ctx + (size_t)(m0 + ch * 8 + rw8) * D_FEAT + k0 + cls, sA + ch * 512);
      }
      for (int j = 0; j < 2; ++j) {
        int ch = wave * 2 + j;
        gload16(Wot + (size_t)(n0 + ch * 8 + rw8) * D_FEAT + k0 + cls, sB + ch * 512);
      }
      __syncthreads();
      for (int kk = 0; kk < 2; ++kk) {
        int c = ((kk * 4 + quad) ^ sw) * 8;
        s16x8 af[4], bfr[2];
        for (int mt = 0; mt < 4; ++mt)
          af[mt] = *(const s16x8*)(sA + (wy * 64 + mt * 16 + l16) * 64 + c);
        for (int nt = 0; nt < 2; ++nt)
          bfr[nt] = *(const s16x8*)(sB + (wx * 32 + nt * 16 + l16) * 64 + c);
        for (int mt = 0; mt < 4; ++mt)
          for (int nt = 0; nt < 2; ++nt)
            acc[mt][nt] = mfma16(af[mt], bfr[nt], acc[mt][nt]);
      }
    }

    for (int mt = 0; mt < 4; ++mt)
      for (int nt = 0; nt < 2; ++nt) {
        int col = n0 + wx * 32 + nt * 16 + l16;
        float bcol = bo[col];
        for (int r = 0; r < 4; ++r) {
          int row = m0 + wy * 64 + mt * 16 + quad * 4 + r;
          tmp[(size_t)row * D_FEAT + col] =
              acc[mt][nt][r] + bcol + v[(size_t)row * D_FEAT + col];
        }
      }
  }
  gbar(bar + 4 * 16);

  // ================= P5: LayerNorm =================
  {
    float* red = (float*)smem;
    for (int i = 0; i < 4; ++i) {
      int row = blk * 4 + i;
      const float* xr = tmp + (size_t)row * D_FEAT;
      float4 vv = ((const float4*)xr)[tid];
      float s  = vv.x + vv.y + vv.z + vv.w;
      float ss = vv.x * vv.x + vv.y * vv.y + vv.z * vv.z + vv.w * vv.w;
      for (int off = 1; off < 64; off <<= 1) {
        s  += __shfl_xor(s,  off, 64);
        ss += __shfl_xor(ss, off, 64);
      }
      if (lane == 0) { red[wave] = s; red[wave + 4] = ss; }
      __syncthreads();
      s  = red[0] + red[1] + red[2] + red[3];
      ss = red[4] + red[5] + red[6] + red[7];
      float mean = s * (1.f / D_FEAT);
      float var  = ss * (1.f / D_FEAT) - mean * mean;
      float rstd = rsqrtf(var + 1e-6f);
      float4 g  = ((const float4*)gamma)[tid];
      float4 bt = ((const float4*)beta)[tid];
      float4 o;
      o.x = (vv.x - mean) * rstd * g.x + bt.x;
      o.y = (vv.y - mean) * rstd * g.y + bt.y;
      o.z = (vv.z - mean) * rstd * g.z + bt.z;
      o.w = (vv.w - mean) * rstd * g.w + bt.w;
      ((float4*)(out + (size_t)row * D_FEAT))[tid] = o;
      __syncthreads();
    }
  }
}

extern "C" void kernel_launch(void* const* d_in, const int* in_sizes, int n_in,
                              void* d_out, int out_size, void* d_ws, size_t ws_size,
                              hipStream_t stream) {
  const float* q     = (const float*)d_in[0];
  const float* k     = (const float*)d_in[1];
  const float* v     = (const float*)d_in[2];
  const float* Wq    = (const float*)d_in[3];
  const float* bq    = (const float*)d_in[4];
  const float* Wk    = (const float*)d_in[5];
  const float* bk    = (const float*)d_in[6];
  const float* Wv    = (const float*)d_in[7];
  const float* bv    = (const float*)d_in[8];
  const float* Wo    = (const float*)d_in[9];
  const float* bo    = (const float*)d_in[10];
  const float* gamma = (const float*)d_in[11];
  const float* beta  = (const float*)d_in[12];

  char* w = (char*)d_ws;
  const size_t MB = 1u << 20;
  // P0/P1: qb 0-8, kb 8-16, vb 16-24, WT 24-30, Wot 30-32
  // P2:    Opart 0-16 (over dead qb/kb), L 16-16.5 (over dead vb)
  // P1/P2: Qp 32-40, Kp 40-48, Vt 48-56
  // P3:    ctx 56-64
  // P4/P5: tmp 32-48 (over dead Qp/Kp)
  // barrier counters at 64 MB, one per phase, 64 B apart
  unsigned short* qb    = (unsigned short*)(w + 0 * MB);
  unsigned short* kb    = (unsigned short*)(w + 8 * MB);
  unsigned short* vb    = (unsigned short*)(w + 16 * MB);
  unsigned short* WT    = (unsigned short*)(w + 24 * MB);
  unsigned short* Wot   = (unsigned short*)(w + 30 * MB);
  unsigned short* Qp    = (unsigned short*)(w + 32 * MB);
  unsigned short* Kp    = (unsigned short*)(w + 40 * MB);
  unsigned short* Vt    = (unsigned short*)(w + 48 * MB);
  unsigned short* ctx   = (unsigned short*)(w + 56 * MB);
  unsigned short* Opart = (unsigned short*)(w + 0 * MB);
  float*          L     = (float*)(w + 16 * MB);
  float*          tmp   = (float*)(w + 32 * MB);
  unsigned*       bar   = (unsigned*)(w + 64 * MB);

  hipMemsetAsync(bar, 0, 512, stream);

  mega_kernel<<<GRID, 256, 0, stream>>>(
      q, k, v, Wq, Wk, Wv, Wo, bq, bk, bv, bo, gamma, beta,
      qb, kb, vb, WT, Wot, Qp, Kp, Vt, Opart, L, ctx, tmp,
      (float*)d_out, bar);
}

// Round 12
// 244.550 us; speedup vs baseline: 3.5968x; 3.4957x over previous
//
#include <hip/hip_runtime.h>

#define D_FEAT 1024
#define NTOK   4096
#define SEQ    2048
#define NHEAD  16
#define DK     64
#define QSCALE 0.1803368801111204f  // 0.125 * log2(e)

typedef float          f32x4  __attribute__((ext_vector_type(4)));
typedef float          f32x16 __attribute__((ext_vector_type(16)));
typedef short          s16x8  __attribute__((ext_vector_type(8)));
typedef unsigned short u16x4  __attribute__((ext_vector_type(4)));

__device__ __forceinline__ unsigned short f2bf(float f) {
  union { float f; unsigned int u; } x; x.f = f;
  unsigned int r = x.u + 0x7fffu + ((x.u >> 16) & 1u);
  return (unsigned short)(r >> 16);
}
__device__ __forceinline__ unsigned short f2h(float f) {
  union { _Float16 h; unsigned short u; } x; x.h = (_Float16)f; return x.u;
}
__device__ __forceinline__ float h2f(unsigned short u) {
  union { _Float16 h; unsigned short u; } x; x.u = u; return (float)x.h;
}

__device__ __forceinline__ f32x4 mfma16(s16x8 a, s16x8 b, f32x4 c) {
  return __builtin_amdgcn_mfma_f32_16x16x32_bf16(a, b, c, 0, 0, 0);
}
__device__ __forceinline__ f32x16 mfma32(s16x8 a, s16x8 b, f32x16 c) {
  return __builtin_amdgcn_mfma_f32_32x32x16_bf16(a, b, c, 0, 0, 0);
}

// async global -> LDS, 16B per lane (dest = wave-uniform base + lane*16)
__device__ __forceinline__ void gload16(const void* g, void* l) {
  __builtin_amdgcn_global_load_lds(
      (const __attribute__((address_space(1))) void*)g,
      (__attribute__((address_space(3))) void*)l, 16, 0, 0);
}

// ---------------- prep: cast q/k/v to bf16 AND transpose+cast weights ----------------
__global__ __launch_bounds__(256) void prep_kernel(
    const float* __restrict__ q, const float* __restrict__ k, const float* __restrict__ v,
    const float* __restrict__ Wq, const float* __restrict__ Wk,
    const float* __restrict__ Wv, const float* __restrict__ Wo,
    unsigned short* __restrict__ qb, unsigned short* __restrict__ kb,
    unsigned short* __restrict__ vb,
    unsigned short* __restrict__ WT, unsigned short* __restrict__ Wot)
{
  __shared__ float tile[32][33];
  const int bx = blockIdx.x, tid = threadIdx.x;
  if (bx < 12288) {
    int sel = bx >> 12;
    const float* src = sel == 0 ? q : (sel == 1 ? k : v);
    unsigned short* dst = sel == 0 ? qb : (sel == 1 ? kb : vb);
    size_t i = ((size_t)(bx & 4095) * 256 + tid) * 4;
    float4 f = *(const float4*)(src + i);
    u16x4 o; o.x = f2bf(f.x); o.y = f2bf(f.y); o.z = f2bf(f.z); o.w = f2bf(f.w);
    *(u16x4*)(dst + i) = o;
  } else {
    int t = bx - 12288;
    int z = t >> 10, rest = t & 1023;
    int bxt = rest & 31, byt = rest >> 5;
    const float* W = z == 0 ? Wq : z == 1 ? Wk : z == 2 ? Wv : Wo;
    unsigned short* T = (z < 3) ? (WT + (size_t)z * 1024 * 1024) : Wot;
    int tx = tid & 31, ty = tid >> 5;
    int n = bxt * 32 + tx;
    for (int i = 0; i < 4; ++i) {
      int kk = byt * 32 + ty + i * 8;
      tile[ty + i * 8][tx] = W[(size_t)kk * D_FEAT + n];
    }
    __syncthreads();
    int kk = byt * 32 + tx;
    for (int i = 0; i < 4; ++i) {
      int n2 = bxt * 32 + ty + i * 8;
      T[(size_t)n2 * D_FEAT + kk] = f2bf(tile[tx][ty + i * 8]);
    }
  }
}

// ---------------- fused QKV projection GEMM (BK=64) -- R7 grid (no XCD swizzle) ----------------
__global__ __launch_bounds__(256, 3) void gemm_qkv(
    const unsigned short* __restrict__ qb, const unsigned short* __restrict__ kb,
    const unsigned short* __restrict__ vb, const unsigned short* __restrict__ WT,
    const float* __restrict__ bq, const float* __restrict__ bk, const float* __restrict__ bv,
    unsigned short* __restrict__ Qp, unsigned short* __restrict__ Kp, unsigned short* __restrict__ Vt)
{
  __shared__ __align__(16) unsigned short sAB[2 * 128 * 64];
  unsigned short* sA = sAB;
  unsigned short* sB = sAB + 128 * 64;
  const int tid = threadIdx.x;
  const int wave = tid >> 6, lane = tid & 63;
  const int quad = lane >> 4, l16 = lane & 15;
  const int wx = wave & 1, wy = wave >> 1;
  const int bx = blockIdx.x;
  const int chunk = bx >> 3;

  const unsigned short* rA;
  const unsigned short* rB;
  int m0, n0;
  if (chunk < 2) {
    m0 = blockIdx.y * 128; n0 = (bx & 7) * 128;
    rA = (chunk ? kb : qb) + (size_t)m0 * D_FEAT;
    rB = WT + (size_t)(chunk * 1024 + n0) * D_FEAT;
  } else {
    m0 = (bx & 7) * 128; n0 = blockIdx.y * 128;
    rA = WT + (size_t)(2048 + m0) * D_FEAT;
    rB = vb + (size_t)n0 * D_FEAT;
  }

  f32x4 acc[4][4];
  for (int mt = 0; mt < 4; ++mt)
    for (int nt = 0; nt < 4; ++nt) acc[mt][nt] = (f32x4){0.f, 0.f, 0.f, 0.f};

  const int rw8 = lane >> 3;
  const int cls = ((lane & 7) ^ (lane >> 3)) * 8;  // swizzled source chunk
  const int sw = l16 & 7;

  for (int k0 = 0; k0 < D_FEAT; k0 += 64) {
    __syncthreads();
    for (int j = 0; j < 4; ++j) {
      int ch = wave * 4 + j;
      gload16(rA + (size_t)(ch * 8 + rw8) * D_FEAT + k0 + cls, sA + ch * 512);
      gload16(rB + (size_t)(ch * 8 + rw8) * D_FEAT + k0 + cls, sB + ch * 512);
    }
    __syncthreads();
    s16x8 af[2][4], bfr[2][4];
    for (int kk = 0; kk < 2; ++kk) {
      int c = ((kk * 4 + quad) ^ sw) * 8;
      for (int mt = 0; mt < 4; ++mt)
        af[kk][mt] = *(const s16x8*)(sA + (wy * 64 + mt * 16 + l16) * 64 + c);
      for (int nt = 0; nt < 4; ++nt)
        bfr[kk][nt] = *(const s16x8*)(sB + (wx * 64 + nt * 16 + l16) * 64 + c);
    }
    for (int kk = 0; kk < 2; ++kk)
      for (int mt = 0; mt < 4; ++mt)
        for (int nt = 0; nt < 4; ++nt)
          acc[mt][nt] = mfma16(af[kk][mt], bfr[kk][nt], acc[mt][nt]);
  }

  if (chunk < 2) {
    const float* bias = chunk ? bk : bq;
    unsigned short* Cp = chunk ? Kp : Qp;
    const float scale = chunk == 0 ? QSCALE : 1.0f;
    for (int mt = 0; mt < 4; ++mt)
      for (int nt = 0; nt < 4; ++nt) {
        int col = n0 + wx * 64 + nt * 16 + l16;
        float bcol = bias[col];
        for (int r = 0; r < 4; ++r) {
          int row = m0 + wy * 64 + mt * 16 + quad * 4 + r;
          Cp[(size_t)row * D_FEAT + col] = f2bf((acc[mt][nt][r] + bcol) * scale);
        }
      }
  } else {
    for (int mt = 0; mt < 4; ++mt)
      for (int r = 0; r < 4; ++r) {
        float bfeat = bv[m0 + wy * 64 + mt * 16 + quad * 4 + r];
        for (int nt = 0; nt < 4; ++nt) acc[mt][nt][r] += bfeat;
      }
    unsigned short* tb = sAB;
    for (int p = 0; p < 2; ++p) {
      __syncthreads();
      if (wx == p) {
        for (int mt = 0; mt < 4; ++mt)
          for (int nt = 0; nt < 4; ++nt) {
            int tok_loc = nt * 16 + l16;
            for (int r = 0; r < 4; ++r) {
              int f_loc = wy * 64 + mt * 16 + quad * 4 + r;
              tb[f_loc * 72 + tok_loc] = f2bf(acc[mt][nt][r]);
            }
          }
      }
      __syncthreads();
      int n_base = n0 + p * 64;
      int b = n_base >> 11, tok0 = n_base & 2047;
      int ck = lane & 7;
      for (int j = 0; j < 4; ++j) {
        int f_loc = (wave * 4 + j) * 8 + rw8;
        int f = m0 + f_loc, hh = f >> 6, dv = f & 63;
        *(s16x8*)(Vt + ((size_t)(b * 16 + hh) * 64 + dv) * SEQ + tok0 + ck * 8) =
            *(const s16x8*)(tb + f_loc * 72 + ck * 8);
      }
    }
  }
}

// ---------------- out-projection GEMM + bias + residual (128x64, BK=64) -- R7 grid ----------------
__global__ __launch_bounds__(256) void gemm_o(
    const unsigned short* __restrict__ A, const unsigned short* __restrict__ Bt,
    const float* __restrict__ bias, const float* __restrict__ resid,
    float* __restrict__ Cout)
{
  __shared__ __align__(16) unsigned short sA[128 * 64];
  __shared__ __align__(16) unsigned short sB[64 * 64];
  const int tid = threadIdx.x;
  const int wave = tid >> 6, lane = tid & 63;
  const int quad = lane >> 4, l16 = lane & 15;
  const int wx = wave & 1, wy = wave >> 1;
  const int n0 = blockIdx.x * 64, m0 = blockIdx.y * 128;

  f32x4 acc[4][2];
  for (int mt = 0; mt < 4; ++mt)
    for (int nt = 0; nt < 2; ++nt) acc[mt][nt] = (f32x4){0.f, 0.f, 0.f, 0.f};

  const int rw8 = lane >> 3;
  const int cls = ((lane & 7) ^ (lane >> 3)) * 8;
  const int sw = l16 & 7;

  for (int k0 = 0; k0 < D_FEAT; k0 += 64) {
    __syncthreads();
    for (int j = 0; j < 4; ++j) {
      int ch = wave * 4 + j;
      gload16(A + (size_t)(m0 + ch * 8 + rw8) * D_FEAT + k0 + cls, sA + ch * 512);
    }
    for (int j = 0; j < 2; ++j) {
      int ch = wave * 2 + j;
      gload16(Bt + (size_t)(n0 + ch * 8 + rw8) * D_FEAT + k0 + cls, sB + ch * 512);
    }
    __syncthreads();
    s16x8 af[2][4], bfr[2][2];
    for (int kk = 0; kk < 2; ++kk) {
      int c = ((kk * 4 + quad) ^ sw) * 8;
      for (int mt = 0; mt < 4; ++mt)
        af[kk][mt] = *(const s16x8*)(sA + (wy * 64 + mt * 16 + l16) * 64 + c);
      for (int nt = 0; nt < 2; ++nt)
        bfr[kk][nt] = *(const s16x8*)(sB + (wx * 32 + nt * 16 + l16) * 64 + c);
    }
    for (int kk = 0; kk < 2; ++kk)
      for (int mt = 0; mt < 4; ++mt)
        for (int nt = 0; nt < 2; ++nt)
          acc[mt][nt] = mfma16(af[kk][mt], bfr[kk][nt], acc[mt][nt]);
  }

  for (int mt = 0; mt < 4; ++mt)
    for (int nt = 0; nt < 2; ++nt) {
      int col = n0 + wx * 32 + nt * 16 + l16;
      float bcol = bias[col];
      for (int r = 0; r < 4; ++r) {
        int row = m0 + wy * 64 + mt * 16 + quad * 4 + r;
        Cout[(size_t)row * D_FEAT + col] =
            acc[mt][nt][r] + bcol + resid[(size_t)row * D_FEAT + col];
      }
    }
}

// ---------------- flash attention, split-S partial pass ----------------
// 1024 blocks = 4/CU exact single fill (required for the per-XCD K/V L2 share).
// P no longer round-trips through LDS: mfma32 S^T layout gives lane (l32,h)
// keys (r&3)+8*(r>>2)+4h; PV B-frag needs keys 16s+8h+j = own pairs + lane^32
// partner pairs -> 16 shfl_xor(32) b32 exchanges + cndmask build the frags
// in-register (kills the sP bank conflicts and the same-wave LDS RAW).
__global__ __launch_bounds__(256, 4) void flash_part(
    const unsigned short* __restrict__ Qp,
    const unsigned short* __restrict__ Kp,
    const unsigned short* __restrict__ Vt,
    unsigned short* __restrict__ Opart,   // [z][bh][tok][dv] fp16
    float* __restrict__ L)                // [z][bh][tok]
{
  __shared__ __align__(16) unsigned short sQ[128 * 64];
  __shared__ __align__(16) unsigned short sK[64 * 64];
  __shared__ __align__(16) unsigned short sV[64 * 64];   // [dv][key]

  const int tid = threadIdx.x;
  const int wave = tid >> 6, lane = tid & 63;
  const int l32 = lane & 31, h = lane >> 5;

  const int blk = blockIdx.x;
  const int xcd = blk & 7, jj = blk >> 3;
  const int grp = xcd * 8 + (jj >> 4);     // (bh,z) group 0..63
  const int q0 = (jj & 15) * 128;
  const int bh = grp & 31, z = grp >> 5;
  const int b = bh >> 4, hd = bh & 15;
  const int kbase = z * (SEQ / 2);
  const size_t base = (size_t)b * SEQ * D_FEAT + (size_t)hd * DK;
  const unsigned short* vt = Vt + (size_t)bh * 64 * SEQ;

  const int rw8 = lane >> 3;
  const int cls = ((lane & 7) ^ (lane >> 3)) * 8;   // swizzled source chunk

  for (int j = 0; j < 4; ++j) {
    int ch = wave * 4 + j;
    gload16(Qp + base + (size_t)(q0 + ch * 8 + rw8) * D_FEAT + cls, sQ + ch * 512);
  }
  __syncthreads();

  const int qrow = wave * 32 + l32;
  const int qsw = qrow & 7;
  s16x8 bq[4];
  for (int s = 0; s < 4; ++s)
    bq[s] = *(const s16x8*)(sQ + qrow * 64 + ((2 * s + h) ^ qsw) * 8);

  f32x16 o0, o1;
  for (int r = 0; r < 16; ++r) { o0[r] = 0.f; o1[r] = 0.f; }
  float lsum = 0.f;

  const int ksw0 = l32 & 7;

  for (int k0 = kbase; k0 < kbase + SEQ / 2; k0 += 64) {
    __syncthreads();
    for (int j = 0; j < 2; ++j) {
      int ch = wave * 2 + j;
      gload16(Kp + base + (size_t)(k0 + ch * 8 + rw8) * D_FEAT + cls, sK + ch * 512);
      gload16(vt + (size_t)(ch * 8 + rw8) * SEQ + k0 + cls, sV + ch * 512);
    }
    __syncthreads();

    f32x16 st0, st1;
    for (int r = 0; r < 16; ++r) { st0[r] = 0.f; st1[r] = 0.f; }
    for (int s = 0; s < 4; ++s) {
      int csw = ((2 * s + h) ^ ksw0) * 8;
      s16x8 a0 = *(const s16x8*)(sK + l32 * 64 + csw);
      s16x8 a1 = *(const s16x8*)(sK + (32 + l32) * 64 + csw);
      st0 = mfma32(a0, bq[s], st0);
      st1 = mfma32(a1, bq[s], st1);
    }

    // P = exp2(S^T): pack adjacent reg pairs to bf16x2 dwords (truncation,
    // same numerics as before -- denominator uses identical values)
    unsigned wv[16], rv[16];
    for (int g = 0; g < 8; ++g) {
      union { float f; unsigned u; } a, c;
      a.f = __builtin_exp2f(st0[2 * g]);     lsum += a.f;
      c.f = __builtin_exp2f(st0[2 * g + 1]); lsum += c.f;
      wv[g] = __builtin_amdgcn_perm(c.u, a.u, 0x07060302u);
    }
    for (int g = 0; g < 8; ++g) {
      union { float f; unsigned u; } a, c;
      a.f = __builtin_exp2f(st1[2 * g]);     lsum += a.f;
      c.f = __builtin_exp2f(st1[2 * g + 1]); lsum += c.f;
      wv[8 + g] = __builtin_amdgcn_perm(c.u, a.u, 0x07060302u);
    }
    for (int i = 0; i < 16; ++i) rv[i] = __shfl_xor(wv[i], 32, 64);

    // build PV B-frags: frag(s) j0-3 = h? recv.hi : own.lo ; j4-7 = h? own.hi : recv.lo
    s16x8 bp[4];
    for (int s = 0; s < 4; ++s) {
      const unsigned* wo = wv + s * 4;
      const unsigned* ro = rv + s * 4;
      union { unsigned u[4]; s16x8 v; } t;
      t.u[0] = h ? ro[2] : wo[0];
      t.u[1] = h ? ro[3] : wo[1];
      t.u[2] = h ? wo[2] : ro[0];
      t.u[3] = h ? wo[3] : ro[1];
      bp[s] = t.v;
    }

    // O^T += V^T P
    for (int s = 0; s < 4; ++s) {
      int csw = ((2 * s + h) ^ ksw0) * 8;
      s16x8 a0 = *(const s16x8*)(sV + l32 * 64 + csw);
      s16x8 a1 = *(const s16x8*)(sV + (32 + l32) * 64 + csw);
      o0 = mfma32(a0, bp[s], o0);
      o1 = mfma32(a1, bp[s], o1);
    }
  }

  // epilogue: unnormalized O^T (fp16) + l (one cross-half shuffle total)
  lsum += __shfl_xor(lsum, 32, 64);
  const size_t trow = (size_t)(z * 32 + bh) * SEQ + (q0 + qrow);
  unsigned short* orow = Opart + trow * 64;
  for (int g = 0; g < 4; ++g) {
    u16x4 ov;
    for (int r = 0; r < 4; ++r) ov[r] = f2h(o0[4 * g + r]);
    *(u16x4*)(orow + 8 * g + 4 * h) = ov;
  }
  for (int g = 0; g < 4; ++g) {
    u16x4 ov;
    for (int r = 0; r < 4; ++r) ov[r] = f2h(o1[4 * g + r]);
    *(u16x4*)(orow + 32 + 8 * g + 4 * h) = ov;
  }
  if (h == 0) L[trow] = lsum;
}

// ---------------- combine the two key-halves -> ctx (bf16) ----------------
__global__ __launch_bounds__(256) void combine_kernel(
    const unsigned short* __restrict__ Opart, const float* __restrict__ L,
    unsigned short* __restrict__ ctx)
{
  const int idx = blockIdx.x * 256 + threadIdx.x;   // 1M total
  const int dq = idx & 15;                          // dv group of 4
  const int trow = idx >> 4;                        // bh*SEQ + tok
  const int bh = trow >> 11, tok = trow & 2047;
  const int b = bh >> 4, h = bh & 15;
  const int HS = 32 * SEQ;                          // half stride (rows)

  float inv = __builtin_amdgcn_rcpf(L[trow] + L[HS + trow]);

  u16x4 p0 = *(const u16x4*)(Opart + (size_t)trow * 64 + dq * 4);
  u16x4 p1 = *(const u16x4*)(Opart + ((size_t)HS + trow) * 64 + dq * 4);
  u16x4 o;
  for (int r = 0; r < 4; ++r)
    o[r] = f2bf((h2f(p0[r]) + h2f(p1[r])) * inv);
  *(u16x4*)(ctx + (size_t)b * SEQ * D_FEAT + (size_t)tok * D_FEAT + h * 64 + dq * 4) = o;
}

// ---------------- LayerNorm over last dim (1024) ----------------
__global__ __launch_bounds__(256) void ln_kernel(
    const float* __restrict__ x, const float* __restrict__ gamma,
    const float* __restrict__ beta, float* __restrict__ out)
{
  const int row = blockIdx.x, tid = threadIdx.x;
  const int wave = tid >> 6, lane = tid & 63;
  const float* xr = x + (size_t)row * D_FEAT;
  float4 v = ((const float4*)xr)[tid];
  float s  = v.x + v.y + v.z + v.w;
  float ss = v.x * v.x + v.y * v.y + v.z * v.z + v.w * v.w;
  for (int off = 1; off < 64; off <<= 1) {
    s  += __shfl_xor(s,  off, 64);
    ss += __shfl_xor(ss, off, 64);
  }
  __shared__ float red[8];
  if (lane == 0) { red[wave] = s; red[wave + 4] = ss; }
  __syncthreads();
  s  = red[0] + red[1] + red[2] + red[3];
  ss = red[4] + red[5] + red[6] + red[7];
  float mean = s * (1.f / D_FEAT);
  float var  = ss * (1.f / D_FEAT) - mean * mean;
  float rstd = rsqrtf(var + 1e-6f);
  float4 g  = ((const float4*)gamma)[tid];
  float4 bt = ((const float4*)beta)[tid];
  float4 o;
  o.x = (v.x - mean) * rstd * g.x + bt.x;
  o.y = (v.y - mean) * rstd * g.y + bt.y;
  o.z = (v.z - mean) * rstd * g.z + bt.z;
  o.w = (v.w - mean) * rstd * g.w + bt.w;
  ((float4*)(out + (size_t)row * D_FEAT))[tid] = o;
}

extern "C" void kernel_launch(void* const* d_in, const int* in_sizes, int n_in,
                              void* d_out, int out_size, void* d_ws, size_t ws_size,
                              hipStream_t stream) {
  const float* q     = (const float*)d_in[0];
  const float* k     = (const float*)d_in[1];
  const float* v     = (const float*)d_in[2];
  const float* Wq    = (const float*)d_in[3];
  const float* bq    = (const float*)d_in[4];
  const float* Wk    = (const float*)d_in[5];
  const float* bk    = (const float*)d_in[6];
  const float* Wv    = (const float*)d_in[7];
  const float* bv    = (const float*)d_in[8];
  const float* Wo    = (const float*)d_in[9];
  const float* bo    = (const float*)d_in[10];
  const float* gamma = (const float*)d_in[11];
  const float* beta  = (const float*)d_in[12];

  char* w = (char*)d_ws;
  const size_t MB = 1u << 20;
  unsigned short* qb    = (unsigned short*)(w + 0 * MB);
  unsigned short* kb    = (unsigned short*)(w + 8 * MB);
  unsigned short* vb    = (unsigned short*)(w + 16 * MB);
  unsigned short* WT    = (unsigned short*)(w + 24 * MB);
  unsigned short* Wot   = (unsigned short*)(w + 30 * MB);
  unsigned short* Qp    = (unsigned short*)(w + 32 * MB);
  unsigned short* Kp    = (unsigned short*)(w + 40 * MB);
  unsigned short* Vt    = (unsigned short*)(w + 48 * MB);  // [bh][dv][tok]
  unsigned short* ctx   = (unsigned short*)(w + 56 * MB);
  float*          tmp   = (float*)(w + 64 * MB);           // 16 MB
  unsigned short* Opart = (unsigned short*)(w + 0 * MB);   // 16 MB fp16 (aliases qb/kb)
  float*          L     = (float*)(w + 16 * MB);           // 0.5 MB (aliases vb)

  prep_kernel<<<16384, 256, 0, stream>>>(q, k, v, Wq, Wk, Wv, Wo, qb, kb, vb, WT, Wot);

  gemm_qkv<<<dim3(24, 32), 256, 0, stream>>>(qb, kb, vb, WT, bq, bk, bv, Qp, Kp, Vt);

  flash_part<<<1024, 256, 0, stream>>>(Qp, Kp, Vt, Opart, L);

  combine_kernel<<<4096, 256, 0, stream>>>(Opart, L, ctx);

  gemm_o<<<dim3(16, 32), 256, 0, stream>>>(ctx, Wot, bo, v, tmp);

  ln_kernel<<<NTOK, 256, 0, stream>>>(tmp, gamma, beta, (float*)d_out);
}